// Round 9
// baseline (332.608 us; speedup 1.0000x reference)
//
#include <hip/hip_runtime.h>
#include <hip/hip_bf16.h>
#include <math.h>

// Sizes (fixed by the reference)
#define GG   4096
#define NNODE 64
#define EEDGE 256
#define FFEAT 64
#define DDIM 128
#define EP   32768

// ---------------------------------------------------------------------------
// Prep (once per call, tiny): Wgf1 = Wg @ Wf1 [64x16],
// bcomb = bg @ Wf1 + bf1 [16], bg32 = 32*bg [128].
// ---------------------------------------------------------------------------
__global__ void k_prep(const float* __restrict__ Wg, const float* __restrict__ Wf1,
                       const float* __restrict__ bf1, const float* __restrict__ bg,
                       float* __restrict__ Wgf1, float* __restrict__ bcomb,
                       float* __restrict__ bg32) {
    int t = threadIdx.x;
    for (int o = t; o < 1024; o += 256) {
        int f = o >> 4, j = o & 15;
        float s = 0.f;
        for (int d = 0; d < 128; ++d) s += Wg[f * 128 + d] * Wf1[d * 16 + j];
        Wgf1[o] = s;
    }
    if (t < 16) {
        float s = bf1[t];
        for (int d = 0; d < 128; ++d) s += bg[d] * Wf1[d * 16 + t];
        bcomb[t] = s;
    }
    if (t >= 128) bg32[t - 128] = 32.0f * bg[t - 128];
}

// ---------------------------------------------------------------------------
// Batched thin GEMM: xwg = x @ Wgf1  ([G*N, 64] @ [64,16]).
// 512 blocks x 256 threads; thread computes 2 rows x 16 cols. W staged in
// LDS; all 64 lanes read the SAME W address -> broadcast, conflict-free.
// ---------------------------------------------------------------------------
__global__ __launch_bounds__(256) void k_xw(
    const float* __restrict__ x, const float* __restrict__ Wgf1,
    float* __restrict__ xwg)
{
    __shared__ __align__(16) float Ws[1024];
    const int t = threadIdx.x;
    for (int i = t; i < 1024; i += 256) Ws[i] = Wgf1[i];
    __syncthreads();
    const size_t r0 = (size_t)blockIdx.x * 512 + t;   // rows r0 and r0+256
    const float* x0 = x + r0 * 64;
    const float* x1 = x + (r0 + 256) * 64;
    float4 z = {0, 0, 0, 0};
    float4 c00 = z, c01 = z, c02 = z, c03 = z;
    float4 c10 = z, c11 = z, c12 = z, c13 = z;
#pragma unroll
    for (int k4 = 0; k4 < 16; ++k4) {
        float4 a0 = *(const float4*)&x0[k4 * 4];
        float4 a1 = *(const float4*)&x1[k4 * 4];
#define STEP(KK, E) { \
        const float* wr = &Ws[(k4 * 4 + (KK)) * 16]; \
        float4 w0 = *(const float4*)wr,       w1 = *(const float4*)(wr + 4); \
        float4 w2 = *(const float4*)(wr + 8), w3 = *(const float4*)(wr + 12); \
        c00.x += a0.E * w0.x; c00.y += a0.E * w0.y; c00.z += a0.E * w0.z; c00.w += a0.E * w0.w; \
        c01.x += a0.E * w1.x; c01.y += a0.E * w1.y; c01.z += a0.E * w1.z; c01.w += a0.E * w1.w; \
        c02.x += a0.E * w2.x; c02.y += a0.E * w2.y; c02.z += a0.E * w2.z; c02.w += a0.E * w2.w; \
        c03.x += a0.E * w3.x; c03.y += a0.E * w3.y; c03.z += a0.E * w3.z; c03.w += a0.E * w3.w; \
        c10.x += a1.E * w0.x; c10.y += a1.E * w0.y; c10.z += a1.E * w0.z; c10.w += a1.E * w0.w; \
        c11.x += a1.E * w1.x; c11.y += a1.E * w1.y; c11.z += a1.E * w1.z; c11.w += a1.E * w1.w; \
        c12.x += a1.E * w2.x; c12.y += a1.E * w2.y; c12.z += a1.E * w2.z; c12.w += a1.E * w2.w; \
        c13.x += a1.E * w3.x; c13.y += a1.E * w3.y; c13.z += a1.E * w3.z; c13.w += a1.E * w3.w; }
        STEP(0, x) STEP(1, y) STEP(2, z) STEP(3, w)
#undef STEP
    }
    float* o0 = &xwg[r0 * 16];
    *(float4*)&o0[0] = c00; *(float4*)&o0[4] = c01;
    *(float4*)&o0[8] = c02; *(float4*)&o0[12] = c03;
    float* o1 = &xwg[(r0 + 256) * 16];
    *(float4*)&o1[0] = c10; *(float4*)&o1[4] = c11;
    *(float4*)&o1[8] = c12; *(float4*)&o1[12] = c13;
}

// ---------------------------------------------------------------------------
// Per-graph kernel v3. Round-8 post-mortem: occupancy 29->38% didn't move
// time -> bound by the serialized phase chain, so shrink the chain:
//  * a1 = tanh(A(x Wgf1) + bcomb): gather in 16-wide space (xw from k_xw);
//    the old 64-wide gather + 64x64@64x16 LDS GEMM (P5) are gone.
//  * Qh = 0.5 (A^T Ssum)^T x: 64-vector w via LDS atomics, then coalesced
//    GLOBAL x reads - no x staging in LDS.
// LDS 18.8 KB -> 8 blocks/CU.
// ---------------------------------------------------------------------------
__global__ __launch_bounds__(256) void k_pg(
    const float* __restrict__ x, const float* __restrict__ xwg,
    const int* __restrict__ ei, const float* __restrict__ ew,
    const float* __restrict__ bcomb,
    const float* __restrict__ Wf2, const float* __restrict__ bf2,
    float* __restrict__ Qh, float* __restrict__ pens)
{
    __shared__ __align__(16) float sm[4688];
    float* xws   = sm;                    // 64 x 20 (cols 0..15 used, 4-aligned)
    float* a1s   = sm + 1280;             // 1024 (later: Qh partials 256)
    int*   srcs  = (int*)(sm + 2304);     // 256
    int*   dsts  = (int*)(sm + 2560);     // 256
    float* lwx   = sm + 2816;             // 256 laplacian lw
    int*   lsrc  = (int*)(sm + 3072);     // 256 CSR src
    float* lnrm  = sm + 3328;             // 256 CSR norm
    float* enrm  = sm + 3584;             // 256 edge-ordered gcn norm
    int*   icnt  = (int*)(sm + 3840);     // 64
    int*   offs  = (int*)(sm + 3904);     // 64
    int*   curs  = (int*)(sm + 3968);     // 64
    float* degw  = sm + 4032;             // 64
    float* dinvs = sm + 4096;             // 64
    float* deg2s = sm + 4160;             // 64
    float* dinv2s= sm + 4224;             // 64
    float* wv    = sm + 4288;             // 64  (w = A^T Ssum)
    float* Ss    = sm + 4352;             // 128
    float* Ssum  = sm + 4480;             // 64
    float* LSs   = sm + 4544;             // 128
    float* bcs   = sm + 4672;             // 16 -> total 4688

    const int g = blockIdx.x;
    const int t = threadIdx.x;

    // P0: edge data into registers + LDS; stage xw tile; zero counters
    const int* eg = ei + (size_t)g * 512;
    const int sR = eg[t];
    const int dR = eg[256 + t];
    const float wR = ew[(size_t)g * 256 + t];
    {
        int n = t >> 2, j4 = (t & 3) * 4;
        float4 v = *(const float4*)&xwg[(size_t)g * 1024 + n * 16 + j4];
        *(float4*)&xws[n * 20 + j4] = v;
    }
    srcs[t] = sR; dsts[t] = dR;
    if (t < 16) bcs[t] = bcomb[t];
    if (t < 64) { icnt[t] = 0; degw[t] = 1.0f; deg2s[t] = 0.0f; }
    if (t < 128) LSs[t] = 0.0f;
    __syncthreads();

    // P1: counts + weighted degrees (from registers)
    atomicAdd(&icnt[dR], 1);
    atomicAdd(&degw[dR], wR);
    atomicAdd(&deg2s[sR], wR);
    __syncthreads();

    // P2: wave0 scans counts -> offsets; dinv
    if (t < 64) {
        int v = icnt[t], own = v;
        for (int o = 1; o < 64; o <<= 1) { int u = __shfl_up(v, o); if (t >= o) v += u; }
        int excl = v - own;
        offs[t] = excl; curs[t] = excl;
        dinvs[t] = rsqrtf(degw[t]);
        float dg = deg2s[t];
        dinv2s[t] = dg > 0.0f ? rsqrtf(fmaxf(dg, 1e-30f)) : 0.0f;
    }
    __syncthreads();

    // P3: CSR place; save edge-ordered gcn norm and laplacian lw
    {
        int pos = atomicAdd(&curs[dR], 1);
        float nm = dinvs[sR] * wR * dinvs[dR];
        lsrc[pos] = sR;
        lnrm[pos] = nm;
        enrm[t] = nm;
        lwx[t] = -dinv2s[sR] * wR * dinv2s[dR];
    }
    __syncthreads();

    // P4: 16-wide gather + bias + tanh -> a1 directly
    {
        int n = t >> 2, j4 = (t & 3) * 4;
        float dv = dinvs[n], sc = dv * dv;
        float4 A = *(const float4*)&xws[n * 20 + j4];
        A.x *= sc; A.y *= sc; A.z *= sc; A.w *= sc;
        int o = offs[n], c = icnt[n];
        for (int j = 0; j < c; ++j) {
            int s = lsrc[o + j];
            float nm = lnrm[o + j];
            float4 X = *(const float4*)&xws[s * 20 + j4];
            A.x += X.x * nm; A.y += X.y * nm; A.z += X.z * nm; A.w += X.w * nm;
        }
        float4 bb = *(const float4*)&bcs[j4];
        a1s[n * 16 + j4 + 0] = tanhf(A.x + bb.x);
        a1s[n * 16 + j4 + 1] = tanhf(A.y + bb.y);
        a1s[n * 16 + j4 + 2] = tanhf(A.z + bb.z);
        a1s[n * 16 + j4 + 3] = tanhf(A.w + bb.w);
    }
    __syncthreads();

    // P6: S logits
    if (t < 128) {
        int n = t >> 1, kk = t & 1;
        float z = bf2[kk];
#pragma unroll
        for (int j = 0; j < 16; ++j) z += a1s[n * 16 + j] * Wf2[j * 2 + kk];
        Ss[n * 2 + kk] = z;
    }
    __syncthreads();

    // P7: softmax rows + row sums + wv self-term
    if (t < 64) {
        float z0 = Ss[t * 2], z1 = Ss[t * 2 + 1];
        float m = fmaxf(z0, z1);
        float e0 = expf(z0 - m), e1 = expf(z1 - m);
        float inv = 1.0f / (e0 + e1);
        e0 *= inv; e1 *= inv;
        Ss[t * 2] = e0; Ss[t * 2 + 1] = e1;
        float su = e0 + e1;
        Ssum[t] = su;
        wv[t] = dinvs[t] * dinvs[t] * su;
    }
    __syncthreads();

    // P8: LS scatter (identity added at use) + wv edge scatter (w = A^T Ssum)
    for (int i = t; i < 512; i += 256) {
        int e = i >> 1, kk = i & 1;
        atomicAdd(&LSs[srcs[e] * 2 + kk], lwx[e] * Ss[dsts[e] * 2 + kk]);
    }
    atomicAdd(&wv[sR], enrm[t] * Ssum[dR]);
    __syncthreads();

    // P9: penalty (wave0) + Qh = 0.5 * w^T x (coalesced global x reads)
    if (t < 64) {
        float s0 = Ss[t * 2], s1 = Ss[t * 2 + 1];
        float l0 = s0 + LSs[t * 2], l1 = s1 + LSs[t * 2 + 1];
        float p00 = s0 * l0, p01 = s0 * l1, p10 = s1 * l0, p11 = s1 * l1;
        for (int o = 32; o; o >>= 1) {
            p00 += __shfl_down(p00, o); p01 += __shfl_down(p01, o);
            p10 += __shfl_down(p10, o); p11 += __shfl_down(p11, o);
        }
        if (t == 0) {
            float r0 = fmaxf(fabsf(p00) + fabsf(p01), 1e-12f);
            float r1 = fmaxf(fabsf(p10) + fabsf(p11), 1e-12f);
            float d0 = p00 / r0 - 1.0f, d1 = p11 / r1 - 1.0f;
            pens[g] = 0.5f * (d0 * d0 + d1 * d1);
        }
    }
    {
        int k = t & 63, p = t >> 6;
        const float* xg = x + (size_t)g * 4096 + (p * 16) * 64 + k;
        float qk = 0.f;
#pragma unroll
        for (int n = 0; n < 16; ++n)
            qk += wv[p * 16 + n] * xg[n * 64];
        a1s[p * 64 + k] = qk;   // a1s dead after P6; safe (barriers P6/P7/P8)
    }
    __syncthreads();
    if (t < 64)
        Qh[(size_t)g * 64 + t] = 0.5f * (a1s[t] + a1s[64 + t] + a1s[128 + t] + a1s[192 + t]);
}

// ---------------------------------------------------------------------------
// Parallel CSR build over pos_edges (3 small kernels; round-6 showed the
// merged single-block version serializes on one CU).
// ---------------------------------------------------------------------------
__global__ void k_cnt(const int* __restrict__ pd, int* __restrict__ icnt) {
    int e = blockIdx.x * 256 + threadIdx.x;
    atomicAdd(&icnt[pd[e]], 1);
}

__global__ void k_scan(const int* __restrict__ icnt, int* __restrict__ offs,
                       int* __restrict__ curs, float* __restrict__ dinv) {
    __shared__ int wsum[4];
    int t = threadIdx.x;
    int base = t * 16;
    int l0,l1,l2,l3,l4,l5,l6,l7,l8,l9,l10,l11,l12,l13,l14,l15;
    l0=icnt[base+0]; l1=icnt[base+1]; l2=icnt[base+2]; l3=icnt[base+3];
    l4=icnt[base+4]; l5=icnt[base+5]; l6=icnt[base+6]; l7=icnt[base+7];
    l8=icnt[base+8]; l9=icnt[base+9]; l10=icnt[base+10]; l11=icnt[base+11];
    l12=icnt[base+12]; l13=icnt[base+13]; l14=icnt[base+14]; l15=icnt[base+15];
    int s = l0+l1+l2+l3+l4+l5+l6+l7+l8+l9+l10+l11+l12+l13+l14+l15;
    int lane = t & 63, w = t >> 6;
    int v = s;
    for (int o = 1; o < 64; o <<= 1) { int u = __shfl_up(v, o); if (lane >= o) v += u; }
    if (lane == 63) wsum[w] = v;
    __syncthreads();
    int woff = 0;
    for (int i = 0; i < 4; ++i) if (i < w) woff += wsum[i];
    int run = woff + v - s;
#define SC(L, I) offs[base+(I)] = run; curs[base+(I)] = run; \
    dinv[base+(I)] = rsqrtf((float)(L) + 1.0f); run += L;
    SC(l0,0) SC(l1,1) SC(l2,2) SC(l3,3) SC(l4,4) SC(l5,5) SC(l6,6) SC(l7,7)
    SC(l8,8) SC(l9,9) SC(l10,10) SC(l11,11) SC(l12,12) SC(l13,13) SC(l14,14) SC(l15,15)
#undef SC
}

__global__ void k_place(const int* __restrict__ pe, const float* __restrict__ dinv,
                        int* __restrict__ curs, int* __restrict__ csr_src,
                        float* __restrict__ csr_nrm) {
    int e = blockIdx.x * 256 + threadIdx.x;
    int s = pe[e], d = pe[EP + e];
    int pos = atomicAdd(&curs[d], 1);
    csr_src[pos] = s;
    csr_nrm[pos] = dinv[s] * dinv[d];
}

// ---------------------------------------------------------------------------
// CSR gathers: out[g] = in[g]*dinv[g]^2 + sum_{edges->g} in[src]*nrm.
// ---------------------------------------------------------------------------
__global__ void k_gather128(const int* __restrict__ offs, const int* __restrict__ icnt,
                            const int* __restrict__ csr_src, const float* __restrict__ csr_nrm,
                            const float* __restrict__ dinv, const float* __restrict__ in,
                            float* __restrict__ out) {
    int g = blockIdx.x, d = threadIdx.x;  // 128 threads
    float dv = dinv[g];
    float acc = in[(size_t)g * 128 + d] * dv * dv;
    int o = offs[g], c = icnt[g];
    for (int j = 0; j < c; ++j)
        acc += in[(size_t)csr_src[o + j] * 128 + d] * csr_nrm[o + j];
    out[(size_t)g * 128 + d] = acc;
}

__global__ void k_gather256(const int* __restrict__ offs, const int* __restrict__ icnt,
                            const int* __restrict__ csr_src, const float* __restrict__ csr_nrm,
                            const float* __restrict__ dinv, const float* __restrict__ in,
                            float* __restrict__ out) {
    int g = blockIdx.x, d = threadIdx.x;  // 256 threads
    float dv = dinv[g];
    float acc = in[(size_t)g * 256 + d] * dv * dv;
    int o = offs[g], c = icnt[g];
    for (int j = 0; j < c; ++j)
        acc += in[(size_t)csr_src[o + j] * 256 + d] * csr_nrm[o + j];
    out[(size_t)g * 256 + d] = acc;
}

// ---------------------------------------------------------------------------
// Double-buffered tiled fp32 GEMM (unchanged): 64x64 tile, 256 threads,
// 4x4 microtile, BK=32, register-prefetch + 2x LDS buffers.
// Dual-output option: blockIdx.y >= gridDim.y/2 uses B1/bias1/C1 (shared A).
// ---------------------------------------------------------------------------
__global__ __launch_bounds__(256) void k_gemm(
    const float* __restrict__ A,
    const float* __restrict__ B0, const float* __restrict__ bias0, float* __restrict__ C0,
    const float* __restrict__ B1, const float* __restrict__ bias1, float* __restrict__ C1,
    int M, int K, int N, int dorelu)
{
    __shared__ __align__(16) float lds[2 * 4352];
    const float* B = B0; const float* bias = bias0; float* C = C0;
    int by = blockIdx.y;
    if (B1 != nullptr && by >= (int)(gridDim.y >> 1)) {
        B = B1; bias = bias1; C = C1; by -= (gridDim.y >> 1);
    }
    const int mb = blockIdx.x * 64, nbb = by * 64;
    const int t = threadIdx.x;
    const int tm4 = (t >> 4) * 4, tn4 = (t & 15) * 4;
    const int ma = t >> 2, ka = (t & 3) * 8;
    const int kb = t >> 3, nb8 = (t & 7) * 8;

    float4 pa0, pa1, pb0, pb1;
#define LOADT(K0) { \
    const float* Ap = &A[(size_t)(mb + ma) * K + (K0) + ka]; \
    pa0 = *(const float4*)Ap; pa1 = *(const float4*)(Ap + 4); \
    const float* Bp = &B[(size_t)((K0) + kb) * N + nbb + nb8]; \
    pb0 = *(const float4*)Bp; pb1 = *(const float4*)(Bp + 4); }
#define STORET(BUF) { \
    float* At_ = lds + (BUF) * 4352; \
    At_[(ka + 0) * 68 + ma] = pa0.x; At_[(ka + 1) * 68 + ma] = pa0.y; \
    At_[(ka + 2) * 68 + ma] = pa0.z; At_[(ka + 3) * 68 + ma] = pa0.w; \
    At_[(ka + 4) * 68 + ma] = pa1.x; At_[(ka + 5) * 68 + ma] = pa1.y; \
    At_[(ka + 6) * 68 + ma] = pa1.z; At_[(ka + 7) * 68 + ma] = pa1.w; \
    float* Bs_ = lds + (BUF) * 4352 + 2176; \
    *(float4*)&Bs_[kb * 68 + nb8] = pb0; *(float4*)&Bs_[kb * 68 + nb8 + 4] = pb1; }

    float4 ca0 = {0,0,0,0}, ca1 = {0,0,0,0}, ca2 = {0,0,0,0}, ca3 = {0,0,0,0};
    const int nk0 = K >> 5;
    LOADT(0)
    STORET(0)
    __syncthreads();
    for (int it = 0; it < nk0; ++it) {
        if (it + 1 < nk0) LOADT((it + 1) * 32)
        const float* At_ = lds + (it & 1) * 4352;
        const float* Bs_ = At_ + 2176;
#pragma unroll
        for (int k = 0; k < 32; ++k) {
            float4 av = *(const float4*)&At_[k * 68 + tm4];
            float4 bv = *(const float4*)&Bs_[k * 68 + tn4];
            ca0.x += av.x * bv.x; ca0.y += av.x * bv.y; ca0.z += av.x * bv.z; ca0.w += av.x * bv.w;
            ca1.x += av.y * bv.x; ca1.y += av.y * bv.y; ca1.z += av.y * bv.z; ca1.w += av.y * bv.w;
            ca2.x += av.z * bv.x; ca2.y += av.z * bv.y; ca2.z += av.z * bv.z; ca2.w += av.z * bv.w;
            ca3.x += av.w * bv.x; ca3.y += av.w * bv.y; ca3.z += av.w * bv.z; ca3.w += av.w * bv.w;
        }
        if (it + 1 < nk0) {
            STORET((it + 1) & 1)
            __syncthreads();
        }
    }
#undef LOADT
#undef STORET
    float4 bv4 = {0, 0, 0, 0};
    if (bias) bv4 = *(const float4*)&bias[nbb + tn4];
#define CST(I, CV) { \
    float4 v; v.x = CV.x + bv4.x; v.y = CV.y + bv4.y; v.z = CV.z + bv4.z; v.w = CV.w + bv4.w; \
    if (dorelu) { v.x = fmaxf(v.x, 0.f); v.y = fmaxf(v.y, 0.f); v.z = fmaxf(v.z, 0.f); v.w = fmaxf(v.w, 0.f); } \
    *(float4*)&C[(size_t)(mb + tm4 + (I)) * N + nbb + tn4] = v; }
    CST(0, ca0) CST(1, ca1) CST(2, ca2) CST(3, ca3)
#undef CST
}

// z = mu + eps*exp(min(ls,10)); zc = [emb, z]; per-graph KL partial
__global__ void k_fin_z(const float* __restrict__ mu_arr, const float* __restrict__ ls_arr,
                        const float* __restrict__ eps, const float* __restrict__ emb,
                        float* __restrict__ zc, float* __restrict__ klp) {
    __shared__ float smw[2];
    int g = blockIdx.x, d = threadIdx.x;  // 128 threads
    int idx = g * 128 + d;
    float mu = mu_arr[idx];
    float ls = fminf(ls_arr[idx], 10.0f);
    float z = mu + eps[idx] * expf(ls);
    zc[(size_t)g * 256 + d] = emb[idx];
    zc[(size_t)g * 256 + 128 + d] = z;
    float term = 1.0f + 2.0f * ls - mu * mu - expf(2.0f * ls);
    for (int o = 32; o; o >>= 1) term += __shfl_down(term, o);
    if ((d & 63) == 0) smw[d >> 6] = term;
    __syncthreads();
    if (d == 0) klp[g] = smw[0] + smw[1];
}

// Edge predictions, 16 lanes per edge (4 edges in flight per wave, 4-step
// reduce): sigmoid(dot(A[src], B[dst])) + per-block log partial (16 edges).
__global__ void k_pred(const float* __restrict__ A, const float* __restrict__ B,
                       const int* __restrict__ pos, const int* __restrict__ neg,
                       float* __restrict__ out, float* __restrict__ predp) {
    __shared__ float smw[16];
    int t = threadIdx.x, sub = t >> 4, l = t & 15;
    int eg = blockIdx.x * 16 + sub;
    int isneg = eg >= EP;
    int e = eg - (isneg ? EP : 0);
    const int* eix = isneg ? neg : pos;
    int s = eix[e], d = eix[EP + e];
    const float4* Ar = (const float4*)(A + (size_t)s * 256);
    const float4* Br = (const float4*)(B + (size_t)d * 256);
    float dot = 0.f;
#pragma unroll
    for (int q = 0; q < 4; ++q) {
        float4 av = Ar[l + 16 * q], bv = Br[l + 16 * q];
        dot += av.x * bv.x + av.y * bv.y + av.z * bv.z + av.w * bv.w;
    }
    for (int o = 8; o; o >>= 1) dot += __shfl_down(dot, o);
    if (l == 0) {
        float p = 1.0f / (1.0f + expf(-dot));
        float term;
        if (isneg) { out[2 + EP + e] = p; term = logf(1.0f - p + 1e-15f); }
        else       { out[2 + e] = p;      term = logf(p + 1e-15f); }
        smw[sub] = term;
    }
    __syncthreads();
    if (t == 0) {
        float s16 = 0.f;
#pragma unroll
        for (int i = 0; i < 16; ++i) s16 += smw[i];
        predp[blockIdx.x] = s16;
    }
}

// Final scalar reductions (predp 4096 entries: 2048 pos + 2048 neg)
__global__ void k_final(const float* __restrict__ pens, const float* __restrict__ klp,
                        const float* __restrict__ predp, float* __restrict__ out) {
    __shared__ float sm[16];
    int t = threadIdx.x;
    float s_pen = 0.f, s_kl = 0.f, s_pos = 0.f, s_neg = 0.f;
    for (int i = t; i < 4096; i += 256) { s_pen += pens[i]; s_kl += klp[i]; }
    for (int i = t; i < 2048; i += 256) { s_pos += predp[i]; s_neg += predp[2048 + i]; }
    for (int o = 32; o; o >>= 1) {
        s_pen += __shfl_down(s_pen, o); s_kl += __shfl_down(s_kl, o);
        s_pos += __shfl_down(s_pos, o); s_neg += __shfl_down(s_neg, o);
    }
    int w = t >> 6;
    if ((t & 63) == 0) { sm[w] = s_pen; sm[4 + w] = s_kl; sm[8 + w] = s_pos; sm[12 + w] = s_neg; }
    __syncthreads();
    if (t == 0) {
        float pen = sm[0] + sm[1] + sm[2] + sm[3];
        float kls = sm[4] + sm[5] + sm[6] + sm[7];
        float pos = sm[8] + sm[9] + sm[10] + sm[11];
        float neg = sm[12] + sm[13] + sm[14] + sm[15];
        float rec = -(pos / 32768.0f) - (neg / 32768.0f);
        out[0] = rec - 0.5f * kls / (4096.0f * 4096.0f);
        out[1] = pen * (1.0f / 4096.0f);
    }
}

extern "C" void kernel_launch(void* const* d_in, const int* in_sizes, int n_in,
                              void* d_out, int out_size, void* d_ws, size_t ws_size,
                              hipStream_t stream) {
    const float* x   = (const float*)d_in[0];
    const int*   ei  = (const int*)d_in[1];
    const float* ew  = (const float*)d_in[2];
    const int*   pos = (const int*)d_in[3];
    const int*   neg = (const int*)d_in[4];
    const float* eps = (const float*)d_in[5];
    const float* Wg  = (const float*)d_in[6];
    const float* bg  = (const float*)d_in[7];
    const float* Wf1 = (const float*)d_in[8];
    const float* bf1 = (const float*)d_in[9];
    const float* Wf2 = (const float*)d_in[10];
    const float* bf2 = (const float*)d_in[11];
    const float* Wc1 = (const float*)d_in[12];
    const float* bc1 = (const float*)d_in[13];
    const float* Wmu = (const float*)d_in[14];
    const float* bmu = (const float*)d_in[15];
    const float* Wls = (const float*)d_in[16];
    const float* bls = (const float*)d_in[17];
    const float* emb = (const float*)d_in[18];
    const float* Wl1 = (const float*)d_in[19];
    const float* bl1 = (const float*)d_in[20];
    const float* Wl2 = (const float*)d_in[21];
    const float* bl2 = (const float*)d_in[22];
    float* out = (float*)d_out;
    float* ws  = (float*)d_ws;

    // Workspace layout (floats), ~30.8 MB. xwg (16 MB) ALIASES the
    // h/ha/mu/ls/zc region: alive only k_xw -> k_pg, all aliased buffers are
    // written strictly after k_pg completes.
    float* g_embs  = ws + 0;         // 524288
    float* dinv    = ws + 524288;    // 4096
    int*   icnt_g  = (int*)(ws + 528384);  // 4096
    int*   off_g   = (int*)(ws + 532480);  // 4096
    int*   cur_g   = (int*)(ws + 536576);  // 4096
    int*   csr_src = (int*)(ws + 540672);  // 32768
    float* csr_nrm = ws + 573440;    // 32768
    float* Qh      = ws + 606208;    // 262144
    float* ga      = ws + 868352;    // 524288
    float* h       = ws + 1392640;   // 1048576
    float* xwg     = ws + 1392640;   // 4194304 (alias: h..zc region)
    float* ha      = ws + 2441216;   // 1048576
    float* mu_arr  = ws + 3489792;   // 524288
    float* ls_arr  = ws + 4014080;   // 524288
    float* zc      = ws + 4538368;   // 1048576
    float* Abuf    = ws + 5586944;   // 1048576
    float* Bbuf    = ws + 6635520;   // 1048576
    float* pens    = ws + 7684096;   // 4096
    float* klp     = ws + 7688192;   // 4096
    float* predp   = ws + 7692288;   // 4096
    float* Wgf1    = ws + 7708672;   // 1024
    float* bcomb   = ws + 7709696;   // 16
    float* bg32    = ws + 7709712;   // 128

    // Zero the CSR counter (16 KB)
    hipMemsetAsync(icnt_g, 0, 4096u * 4, stream);

    // Prep + batched xw GEMM + per-graph stage
    k_prep<<<1, 256, 0, stream>>>(Wg, Wf1, bf1, bg, Wgf1, bcomb, bg32);
    k_xw<<<512, 256, 0, stream>>>(x, Wgf1, xwg);
    k_pg<<<GG, 256, 0, stream>>>(x, xwg, ei, ew, bcomb, Wf2, bf2, Qh, pens);
    // g_embs = Qh @ Wg + 32*bg
    k_gemm<<<dim3(64, 2), 256, 0, stream>>>(Qh, Wg, bg32, g_embs,
                                            nullptr, nullptr, nullptr, GG, 64, 128, 0);

    // Parallel CSR build over pos_edges
    k_cnt<<<EP / 256, 256, 0, stream>>>(pos + EP, icnt_g);
    k_scan<<<1, 256, 0, stream>>>(icnt_g, off_g, cur_g, dinv);
    k_place<<<EP / 256, 256, 0, stream>>>(pos, dinv, cur_g, csr_src, csr_nrm);

    // h = relu((A g_embs) @ Wc1 + bc1)
    k_gather128<<<GG, 128, 0, stream>>>(off_g, icnt_g, csr_src, csr_nrm, dinv, g_embs, ga);
    k_gemm<<<dim3(64, 4), 256, 0, stream>>>(ga, Wc1, bc1, h,
                                            nullptr, nullptr, nullptr, GG, 128, 256, 1);

    // mu/ls = (A h) @ {Wmu,Wls} + {bmu,bls}
    k_gather256<<<GG, 256, 0, stream>>>(off_g, icnt_g, csr_src, csr_nrm, dinv, h, ha);
    k_gemm<<<dim3(64, 4), 256, 0, stream>>>(ha, Wmu, bmu, mu_arr,
                                            Wls, bls, ls_arr, GG, 256, 128, 0);
    k_fin_z<<<GG, 128, 0, stream>>>(mu_arr, ls_arr, eps, emb, zc, klp);

    // A = zc@W_lin1+b, B = zc@W_lin2+b
    k_gemm<<<dim3(64, 8), 256, 0, stream>>>(zc, Wl1, bl1, Abuf,
                                            Wl2, bl2, Bbuf, GG, 256, 256, 0);

    // Edge predictions + scalars (16 edges/block)
    k_pred<<<(2 * EP) / 16, 256, 0, stream>>>(Abuf, Bbuf, pos, neg, out, predp);
    k_final<<<1, 256, 0, stream>>>(pens, klp, predp, out);
}

// Round 10
// 321.192 us; speedup vs baseline: 1.0355x; 1.0355x over previous
//
#include <hip/hip_runtime.h>
#include <hip/hip_bf16.h>
#include <math.h>

// Sizes (fixed by the reference)
#define GG   4096
#define NNODE 64
#define EEDGE 256
#define FFEAT 64
#define DDIM 128
#define EP   32768

// ---------------------------------------------------------------------------
// Prep (once per call, tiny): Wgf1 = Wg @ Wf1 [64x16],
// bcomb = bg @ Wf1 + bf1 [16], bg32 = 32*bg [128].
// ---------------------------------------------------------------------------
__global__ void k_prep(const float* __restrict__ Wg, const float* __restrict__ Wf1,
                       const float* __restrict__ bf1, const float* __restrict__ bg,
                       float* __restrict__ Wgf1, float* __restrict__ bcomb,
                       float* __restrict__ bg32) {
    int t = threadIdx.x;
    for (int o = t; o < 1024; o += 256) {
        int f = o >> 4, j = o & 15;
        float s = 0.f;
        for (int d = 0; d < 128; ++d) s += Wg[f * 128 + d] * Wf1[d * 16 + j];
        Wgf1[o] = s;
    }
    if (t < 16) {
        float s = bf1[t];
        for (int d = 0; d < 128; ++d) s += bg[d] * Wf1[d * 16 + t];
        bcomb[t] = s;
    }
    if (t >= 128) bg32[t - 128] = 32.0f * bg[t - 128];
}

// ---------------------------------------------------------------------------
// Per-graph kernel v4. Round-9 post-mortem: separate k_xw (+15 us, +34 MB
// xwg round-trip, x read twice) ate the k_pg win. This version folds the
// xw GEMM back in: x staged in LDS ONCE (read from HBM exactly once,
// coalesced float4), xw computed in-block (overlapped with the count
// atomics), gather stays 16-wide, P9 reads x from LDS via float4.
// LDS 36.2 KB -> 4 blocks/CU.
// ---------------------------------------------------------------------------
__global__ __launch_bounds__(256) void k_pg(
    const float* __restrict__ x, const int* __restrict__ ei, const float* __restrict__ ew,
    const float* __restrict__ Wgf1, const float* __restrict__ bcomb,
    const float* __restrict__ Wf2, const float* __restrict__ bf2,
    float* __restrict__ Qh, float* __restrict__ pens)
{
    __shared__ __align__(16) float sm[9040];
    float* xs    = sm;                    // 64 x 68 (x, stays alive through P9)
    float* Wgf1s = sm + 4352;             // 1024 (dead after P4a)
    float* a1s   = sm + 4352;             // alias: a1 after P4b, Qh partials after P6
    float* xws   = sm + 5376;             // 64 x 20 (xw, cols 0..15)
    int*   srcs  = (int*)(sm + 6656);     // 256
    int*   dsts  = (int*)(sm + 6912);     // 256
    float* lwx   = sm + 7168;             // 256 laplacian lw
    int*   lsrc  = (int*)(sm + 7424);     // 256 CSR src
    float* lnrm  = sm + 7680;             // 256 CSR norm
    float* enrm  = sm + 7936;             // 256 edge-ordered gcn norm
    int*   icnt  = (int*)(sm + 8192);     // 64
    int*   offs  = (int*)(sm + 8256);     // 64
    int*   curs  = (int*)(sm + 8320);     // 64
    float* degw  = sm + 8384;             // 64
    float* dinvs = sm + 8448;             // 64
    float* deg2s = sm + 8512;             // 64
    float* dinv2s= sm + 8576;             // 64
    float* wv    = sm + 8640;             // 64 (w = A^T Ssum)
    float* Ss    = sm + 8704;             // 128
    float* Ssum  = sm + 8832;             // 64
    float* LSs   = sm + 8896;             // 128
    float* bcs   = sm + 9024;             // 16 -> total 9040

    const int g = blockIdx.x;
    const int t = threadIdx.x;

    // P0: stage x (float4, coalesced, once), W, edges; zero counters
    const int* eg = ei + (size_t)g * 512;
    const int sR = eg[t];
    const int dR = eg[256 + t];
    const float wR = ew[(size_t)g * 256 + t];
    {
        const float* xg = x + (size_t)g * 4096;
        for (int i = t; i < 1024; i += 256) {
            int n = i >> 4, k = (i & 15) * 4;
            *(float4*)&xs[n * 68 + k] = *(const float4*)&xg[n * 64 + k];
        }
        for (int i = t; i < 1024; i += 256) Wgf1s[i] = Wgf1[i];
    }
    srcs[t] = sR; dsts[t] = dR;
    if (t < 16) bcs[t] = bcomb[t];
    if (t < 64) { icnt[t] = 0; degw[t] = 1.0f; deg2s[t] = 0.0f; }
    if (t < 128) LSs[t] = 0.0f;
    __syncthreads();

    // P1+P4a: count atomics (fire-and-forget) overlapped with xw GEMM
    atomicAdd(&icnt[dR], 1);
    atomicAdd(&degw[dR], wR);
    atomicAdd(&deg2s[sR], wR);
    {
        // xw[n][j4..j4+3] = sum_k xs[n][k] * Wgf1[k][j4..]; 4 threads/row
        int n = t >> 2, j4 = (t & 3) * 4;
        float4 acc = {0.f, 0.f, 0.f, 0.f};
#pragma unroll 4
        for (int k4 = 0; k4 < 16; ++k4) {
            float4 xq = *(const float4*)&xs[n * 68 + k4 * 4];  // broadcast in quad
#define XWSTEP(E, KK) { \
            float4 w = *(const float4*)&Wgf1s[(k4 * 4 + (KK)) * 16 + j4]; \
            acc.x += xq.E * w.x; acc.y += xq.E * w.y; \
            acc.z += xq.E * w.z; acc.w += xq.E * w.w; }
            XWSTEP(x, 0) XWSTEP(y, 1) XWSTEP(z, 2) XWSTEP(w, 3)
#undef XWSTEP
        }
        *(float4*)&xws[n * 20 + j4] = acc;
    }
    __syncthreads();

    // P2: wave0 scans counts -> offsets; dinv
    if (t < 64) {
        int v = icnt[t], own = v;
        for (int o = 1; o < 64; o <<= 1) { int u = __shfl_up(v, o); if (t >= o) v += u; }
        int excl = v - own;
        offs[t] = excl; curs[t] = excl;
        dinvs[t] = rsqrtf(degw[t]);
        float dg = deg2s[t];
        dinv2s[t] = dg > 0.0f ? rsqrtf(fmaxf(dg, 1e-30f)) : 0.0f;
    }
    __syncthreads();

    // P3: CSR place; edge-ordered gcn norm and laplacian lw
    {
        int pos = atomicAdd(&curs[dR], 1);
        float nm = dinvs[sR] * wR * dinvs[dR];
        lsrc[pos] = sR;
        lnrm[pos] = nm;
        enrm[t] = nm;
        lwx[t] = -dinv2s[sR] * wR * dinv2s[dR];
    }
    __syncthreads();

    // P4b: 16-wide gather + bias + tanh -> a1 (a1s aliases Wgf1s, now dead)
    {
        int n = t >> 2, j4 = (t & 3) * 4;
        float dv = dinvs[n], sc = dv * dv;
        float4 A = *(const float4*)&xws[n * 20 + j4];
        A.x *= sc; A.y *= sc; A.z *= sc; A.w *= sc;
        int o = offs[n], c = icnt[n];
        for (int j = 0; j < c; ++j) {
            int s = lsrc[o + j];
            float nm = lnrm[o + j];
            float4 X = *(const float4*)&xws[s * 20 + j4];
            A.x += X.x * nm; A.y += X.y * nm; A.z += X.z * nm; A.w += X.w * nm;
        }
        float4 bb = *(const float4*)&bcs[j4];
        __syncthreads();   // Wgf1s reads (P4a) fully done before alias write
        a1s[n * 16 + j4 + 0] = tanhf(A.x + bb.x);
        a1s[n * 16 + j4 + 1] = tanhf(A.y + bb.y);
        a1s[n * 16 + j4 + 2] = tanhf(A.z + bb.z);
        a1s[n * 16 + j4 + 3] = tanhf(A.w + bb.w);
    }
    __syncthreads();

    // P6: S logits
    if (t < 128) {
        int n = t >> 1, kk = t & 1;
        float z = bf2[kk];
#pragma unroll
        for (int j = 0; j < 16; ++j) z += a1s[n * 16 + j] * Wf2[j * 2 + kk];
        Ss[n * 2 + kk] = z;
    }
    __syncthreads();

    // P7: softmax rows + row sums + wv self-term
    if (t < 64) {
        float z0 = Ss[t * 2], z1 = Ss[t * 2 + 1];
        float m = fmaxf(z0, z1);
        float e0 = expf(z0 - m), e1 = expf(z1 - m);
        float inv = 1.0f / (e0 + e1);
        e0 *= inv; e1 *= inv;
        Ss[t * 2] = e0; Ss[t * 2 + 1] = e1;
        float su = e0 + e1;
        Ssum[t] = su;
        wv[t] = dinvs[t] * dinvs[t] * su;
    }
    __syncthreads();

    // P8: LS scatter (identity added at use) + wv edge scatter
    for (int i = t; i < 512; i += 256) {
        int e = i >> 1, kk = i & 1;
        atomicAdd(&LSs[srcs[e] * 2 + kk], lwx[e] * Ss[dsts[e] * 2 + kk]);
    }
    atomicAdd(&wv[sR], enrm[t] * Ssum[dR]);
    __syncthreads();

    // P9: penalty (wave0) + Qh = 0.5 * w^T x from LDS (float4)
    if (t < 64) {
        float s0 = Ss[t * 2], s1 = Ss[t * 2 + 1];
        float l0 = s0 + LSs[t * 2], l1 = s1 + LSs[t * 2 + 1];
        float p00 = s0 * l0, p01 = s0 * l1, p10 = s1 * l0, p11 = s1 * l1;
        for (int o = 32; o; o >>= 1) {
            p00 += __shfl_down(p00, o); p01 += __shfl_down(p01, o);
            p10 += __shfl_down(p10, o); p11 += __shfl_down(p11, o);
        }
        if (t == 0) {
            float r0 = fmaxf(fabsf(p00) + fabsf(p01), 1e-12f);
            float r1 = fmaxf(fabsf(p10) + fabsf(p11), 1e-12f);
            float d0 = p00 / r0 - 1.0f, d1 = p11 / r1 - 1.0f;
            pens[g] = 0.5f * (d0 * d0 + d1 * d1);
        }
    }
    {
        // group p = t>>4 covers nodes 4p..4p+3; lane covers 4 k's via float4
        int p = t >> 4, k4 = (t & 15) * 4;
        float4 q = {0.f, 0.f, 0.f, 0.f};
#pragma unroll
        for (int e = 0; e < 4; ++e) {
            int n = p * 4 + e;
            float wn = wv[n];
            float4 xv = *(const float4*)&xs[n * 68 + k4];
            q.x += wn * xv.x; q.y += wn * xv.y; q.z += wn * xv.z; q.w += wn * xv.w;
        }
        *(float4*)&a1s[p * 64 + k4] = q;   // a1s dead after P6 (barriers since)
    }
    __syncthreads();
    if (t < 64) {
        float s = 0.f;
#pragma unroll
        for (int p = 0; p < 16; ++p) s += a1s[p * 64 + t];
        Qh[(size_t)g * 64 + t] = 0.5f * s;
    }
}

// ---------------------------------------------------------------------------
// Parallel CSR build over pos_edges (3 small kernels).
// ---------------------------------------------------------------------------
__global__ void k_cnt(const int* __restrict__ pd, int* __restrict__ icnt) {
    int e = blockIdx.x * 256 + threadIdx.x;
    atomicAdd(&icnt[pd[e]], 1);
}

__global__ void k_scan(const int* __restrict__ icnt, int* __restrict__ offs,
                       int* __restrict__ curs, float* __restrict__ dinv) {
    __shared__ int wsum[4];
    int t = threadIdx.x;
    int base = t * 16;
    int l0,l1,l2,l3,l4,l5,l6,l7,l8,l9,l10,l11,l12,l13,l14,l15;
    l0=icnt[base+0]; l1=icnt[base+1]; l2=icnt[base+2]; l3=icnt[base+3];
    l4=icnt[base+4]; l5=icnt[base+5]; l6=icnt[base+6]; l7=icnt[base+7];
    l8=icnt[base+8]; l9=icnt[base+9]; l10=icnt[base+10]; l11=icnt[base+11];
    l12=icnt[base+12]; l13=icnt[base+13]; l14=icnt[base+14]; l15=icnt[base+15];
    int s = l0+l1+l2+l3+l4+l5+l6+l7+l8+l9+l10+l11+l12+l13+l14+l15;
    int lane = t & 63, w = t >> 6;
    int v = s;
    for (int o = 1; o < 64; o <<= 1) { int u = __shfl_up(v, o); if (lane >= o) v += u; }
    if (lane == 63) wsum[w] = v;
    __syncthreads();
    int woff = 0;
    for (int i = 0; i < 4; ++i) if (i < w) woff += wsum[i];
    int run = woff + v - s;
#define SC(L, I) offs[base+(I)] = run; curs[base+(I)] = run; \
    dinv[base+(I)] = rsqrtf((float)(L) + 1.0f); run += L;
    SC(l0,0) SC(l1,1) SC(l2,2) SC(l3,3) SC(l4,4) SC(l5,5) SC(l6,6) SC(l7,7)
    SC(l8,8) SC(l9,9) SC(l10,10) SC(l11,11) SC(l12,12) SC(l13,13) SC(l14,14) SC(l15,15)
#undef SC
}

__global__ void k_place(const int* __restrict__ pe, const float* __restrict__ dinv,
                        int* __restrict__ curs, int* __restrict__ csr_src,
                        float* __restrict__ csr_nrm) {
    int e = blockIdx.x * 256 + threadIdx.x;
    int s = pe[e], d = pe[EP + e];
    int pos = atomicAdd(&curs[d], 1);
    csr_src[pos] = s;
    csr_nrm[pos] = dinv[s] * dinv[d];
}

// ---------------------------------------------------------------------------
// CSR gathers: out[g] = in[g]*dinv[g]^2 + sum_{edges->g} in[src]*nrm.
// ---------------------------------------------------------------------------
__global__ void k_gather128(const int* __restrict__ offs, const int* __restrict__ icnt,
                            const int* __restrict__ csr_src, const float* __restrict__ csr_nrm,
                            const float* __restrict__ dinv, const float* __restrict__ in,
                            float* __restrict__ out) {
    int g = blockIdx.x, d = threadIdx.x;  // 128 threads
    float dv = dinv[g];
    float acc = in[(size_t)g * 128 + d] * dv * dv;
    int o = offs[g], c = icnt[g];
    for (int j = 0; j < c; ++j)
        acc += in[(size_t)csr_src[o + j] * 128 + d] * csr_nrm[o + j];
    out[(size_t)g * 128 + d] = acc;
}

__global__ void k_gather256(const int* __restrict__ offs, const int* __restrict__ icnt,
                            const int* __restrict__ csr_src, const float* __restrict__ csr_nrm,
                            const float* __restrict__ dinv, const float* __restrict__ in,
                            float* __restrict__ out) {
    int g = blockIdx.x, d = threadIdx.x;  // 256 threads
    float dv = dinv[g];
    float acc = in[(size_t)g * 256 + d] * dv * dv;
    int o = offs[g], c = icnt[g];
    for (int j = 0; j < c; ++j)
        acc += in[(size_t)csr_src[o + j] * 256 + d] * csr_nrm[o + j];
    out[(size_t)g * 256 + d] = acc;
}

// ---------------------------------------------------------------------------
// Double-buffered tiled fp32 GEMM, 32x64 tile (round-10: was 64x64; grids
// were 128-512 blocks = 0.5-2/CU, latency-bound -> halve M-tile to double
// the grid). 256 threads, 2x4 microtile, BK=32, register-prefetch + 2x LDS.
// Dual-output option: blockIdx.y >= gridDim.y/2 uses B1/bias1/C1 (shared A).
// ---------------------------------------------------------------------------
__global__ __launch_bounds__(256) void k_gemm(
    const float* __restrict__ A,
    const float* __restrict__ B0, const float* __restrict__ bias0, float* __restrict__ C0,
    const float* __restrict__ B1, const float* __restrict__ bias1, float* __restrict__ C1,
    int M, int K, int N, int dorelu)
{
    __shared__ __align__(16) float lds[2 * 3328];  // per buf: At 32x36, Bs 32x68
    const float* B = B0; const float* bias = bias0; float* C = C0;
    int by = blockIdx.y;
    if (B1 != nullptr && by >= (int)(gridDim.y >> 1)) {
        B = B1; bias = bias1; C = C1; by -= (gridDim.y >> 1);
    }
    const int mb = blockIdx.x * 32, nbb = by * 64;
    const int t = threadIdx.x;
    const int tm2 = (t >> 4) * 2, tn4 = (t & 15) * 4;
    const int ma = t >> 3, ka = (t & 7) * 4;     // A: (ma, ka..ka+3)
    const int kb = t >> 3, nb8 = (t & 7) * 8;    // B: (kb, nb8..nb8+7)

    float4 pa0, pb0, pb1;
#define LOADT(K0) { \
    pa0 = *(const float4*)&A[(size_t)(mb + ma) * K + (K0) + ka]; \
    const float* Bp = &B[(size_t)((K0) + kb) * N + nbb + nb8]; \
    pb0 = *(const float4*)Bp; pb1 = *(const float4*)(Bp + 4); }
#define STORET(BUF) { \
    float* At_ = lds + (BUF) * 3328; \
    At_[(ka + 0) * 36 + ma] = pa0.x; At_[(ka + 1) * 36 + ma] = pa0.y; \
    At_[(ka + 2) * 36 + ma] = pa0.z; At_[(ka + 3) * 36 + ma] = pa0.w; \
    float* Bs_ = lds + (BUF) * 3328 + 1152; \
    *(float4*)&Bs_[kb * 68 + nb8] = pb0; *(float4*)&Bs_[kb * 68 + nb8 + 4] = pb1; }

    float4 ca0 = {0,0,0,0}, ca1 = {0,0,0,0};
    const int nk0 = K >> 5;
    LOADT(0)
    STORET(0)
    __syncthreads();
    for (int it = 0; it < nk0; ++it) {
        if (it + 1 < nk0) LOADT((it + 1) * 32)
        const float* At_ = lds + (it & 1) * 3328;
        const float* Bs_ = At_ + 1152;
#pragma unroll
        for (int k = 0; k < 32; ++k) {
            float2 av = *(const float2*)&At_[k * 36 + tm2];
            float4 bv = *(const float4*)&Bs_[k * 68 + tn4];
            ca0.x += av.x * bv.x; ca0.y += av.x * bv.y; ca0.z += av.x * bv.z; ca0.w += av.x * bv.w;
            ca1.x += av.y * bv.x; ca1.y += av.y * bv.y; ca1.z += av.y * bv.z; ca1.w += av.y * bv.w;
        }
        if (it + 1 < nk0) {
            STORET((it + 1) & 1)
            __syncthreads();
        }
    }
#undef LOADT
#undef STORET
    float4 bv4 = {0, 0, 0, 0};
    if (bias) bv4 = *(const float4*)&bias[nbb + tn4];
#define CST(I, CV) { \
    float4 v; v.x = CV.x + bv4.x; v.y = CV.y + bv4.y; v.z = CV.z + bv4.z; v.w = CV.w + bv4.w; \
    if (dorelu) { v.x = fmaxf(v.x, 0.f); v.y = fmaxf(v.y, 0.f); v.z = fmaxf(v.z, 0.f); v.w = fmaxf(v.w, 0.f); } \
    *(float4*)&C[(size_t)(mb + tm2 + (I)) * N + nbb + tn4] = v; }
    CST(0, ca0) CST(1, ca1)
#undef CST
}

// z = mu + eps*exp(min(ls,10)); zc = [emb, z]; per-graph KL partial
__global__ void k_fin_z(const float* __restrict__ mu_arr, const float* __restrict__ ls_arr,
                        const float* __restrict__ eps, const float* __restrict__ emb,
                        float* __restrict__ zc, float* __restrict__ klp) {
    __shared__ float smw[2];
    int g = blockIdx.x, d = threadIdx.x;  // 128 threads
    int idx = g * 128 + d;
    float mu = mu_arr[idx];
    float ls = fminf(ls_arr[idx], 10.0f);
    float z = mu + eps[idx] * expf(ls);
    zc[(size_t)g * 256 + d] = emb[idx];
    zc[(size_t)g * 256 + 128 + d] = z;
    float term = 1.0f + 2.0f * ls - mu * mu - expf(2.0f * ls);
    for (int o = 32; o; o >>= 1) term += __shfl_down(term, o);
    if ((d & 63) == 0) smw[d >> 6] = term;
    __syncthreads();
    if (d == 0) klp[g] = smw[0] + smw[1];
}

// Edge predictions, 16 lanes per edge (4 edges in flight per wave):
// sigmoid(dot(A[src], B[dst])) + per-block log partial (16 edges).
__global__ void k_pred(const float* __restrict__ A, const float* __restrict__ B,
                       const int* __restrict__ pos, const int* __restrict__ neg,
                       float* __restrict__ out, float* __restrict__ predp) {
    __shared__ float smw[16];
    int t = threadIdx.x, sub = t >> 4, l = t & 15;
    int eg = blockIdx.x * 16 + sub;
    int isneg = eg >= EP;
    int e = eg - (isneg ? EP : 0);
    const int* eix = isneg ? neg : pos;
    int s = eix[e], d = eix[EP + e];
    const float4* Ar = (const float4*)(A + (size_t)s * 256);
    const float4* Br = (const float4*)(B + (size_t)d * 256);
    float dot = 0.f;
#pragma unroll
    for (int q = 0; q < 4; ++q) {
        float4 av = Ar[l + 16 * q], bv = Br[l + 16 * q];
        dot += av.x * bv.x + av.y * bv.y + av.z * bv.z + av.w * bv.w;
    }
    for (int o = 8; o; o >>= 1) dot += __shfl_down(dot, o);
    if (l == 0) {
        float p = 1.0f / (1.0f + expf(-dot));
        float term;
        if (isneg) { out[2 + EP + e] = p; term = logf(1.0f - p + 1e-15f); }
        else       { out[2 + e] = p;      term = logf(p + 1e-15f); }
        smw[sub] = term;
    }
    __syncthreads();
    if (t == 0) {
        float s16 = 0.f;
#pragma unroll
        for (int i = 0; i < 16; ++i) s16 += smw[i];
        predp[blockIdx.x] = s16;
    }
}

// Final scalar reductions (predp 4096 entries: 2048 pos + 2048 neg)
__global__ void k_final(const float* __restrict__ pens, const float* __restrict__ klp,
                        const float* __restrict__ predp, float* __restrict__ out) {
    __shared__ float sm[16];
    int t = threadIdx.x;
    float s_pen = 0.f, s_kl = 0.f, s_pos = 0.f, s_neg = 0.f;
    for (int i = t; i < 4096; i += 256) { s_pen += pens[i]; s_kl += klp[i]; }
    for (int i = t; i < 2048; i += 256) { s_pos += predp[i]; s_neg += predp[2048 + i]; }
    for (int o = 32; o; o >>= 1) {
        s_pen += __shfl_down(s_pen, o); s_kl += __shfl_down(s_kl, o);
        s_pos += __shfl_down(s_pos, o); s_neg += __shfl_down(s_neg, o);
    }
    int w = t >> 6;
    if ((t & 63) == 0) { sm[w] = s_pen; sm[4 + w] = s_kl; sm[8 + w] = s_pos; sm[12 + w] = s_neg; }
    __syncthreads();
    if (t == 0) {
        float pen = sm[0] + sm[1] + sm[2] + sm[3];
        float kls = sm[4] + sm[5] + sm[6] + sm[7];
        float pos = sm[8] + sm[9] + sm[10] + sm[11];
        float neg = sm[12] + sm[13] + sm[14] + sm[15];
        float rec = -(pos / 32768.0f) - (neg / 32768.0f);
        out[0] = rec - 0.5f * kls / (4096.0f * 4096.0f);
        out[1] = pen * (1.0f / 4096.0f);
    }
}

extern "C" void kernel_launch(void* const* d_in, const int* in_sizes, int n_in,
                              void* d_out, int out_size, void* d_ws, size_t ws_size,
                              hipStream_t stream) {
    const float* x   = (const float*)d_in[0];
    const int*   ei  = (const int*)d_in[1];
    const float* ew  = (const float*)d_in[2];
    const int*   pos = (const int*)d_in[3];
    const int*   neg = (const int*)d_in[4];
    const float* eps = (const float*)d_in[5];
    const float* Wg  = (const float*)d_in[6];
    const float* bg  = (const float*)d_in[7];
    const float* Wf1 = (const float*)d_in[8];
    const float* bf1 = (const float*)d_in[9];
    const float* Wf2 = (const float*)d_in[10];
    const float* bf2 = (const float*)d_in[11];
    const float* Wc1 = (const float*)d_in[12];
    const float* bc1 = (const float*)d_in[13];
    const float* Wmu = (const float*)d_in[14];
    const float* bmu = (const float*)d_in[15];
    const float* Wls = (const float*)d_in[16];
    const float* bls = (const float*)d_in[17];
    const float* emb = (const float*)d_in[18];
    const float* Wl1 = (const float*)d_in[19];
    const float* bl1 = (const float*)d_in[20];
    const float* Wl2 = (const float*)d_in[21];
    const float* bl2 = (const float*)d_in[22];
    float* out = (float*)d_out;
    float* ws  = (float*)d_ws;

    // Workspace layout (floats), ~30.8 MB
    float* g_embs  = ws + 0;         // 524288
    float* dinv    = ws + 524288;    // 4096
    int*   icnt_g  = (int*)(ws + 528384);  // 4096
    int*   off_g   = (int*)(ws + 532480);  // 4096
    int*   cur_g   = (int*)(ws + 536576);  // 4096
    int*   csr_src = (int*)(ws + 540672);  // 32768
    float* csr_nrm = ws + 573440;    // 32768
    float* Qh      = ws + 606208;    // 262144
    float* ga      = ws + 868352;    // 524288
    float* h       = ws + 1392640;   // 1048576
    float* ha      = ws + 2441216;   // 1048576
    float* mu_arr  = ws + 3489792;   // 524288
    float* ls_arr  = ws + 4014080;   // 524288
    float* zc      = ws + 4538368;   // 1048576
    float* Abuf    = ws + 5586944;   // 1048576
    float* Bbuf    = ws + 6635520;   // 1048576
    float* pens    = ws + 7684096;   // 4096
    float* klp     = ws + 7688192;   // 4096
    float* predp   = ws + 7692288;   // 4096
    float* Wgf1    = ws + 7708672;   // 1024
    float* bcomb   = ws + 7709696;   // 16
    float* bg32    = ws + 7709712;   // 128

    // Zero the CSR counter (16 KB)
    hipMemsetAsync(icnt_g, 0, 4096u * 4, stream);

    // Prep + per-graph stage (xw GEMM folded into k_pg)
    k_prep<<<1, 256, 0, stream>>>(Wg, Wf1, bf1, bg, Wgf1, bcomb, bg32);
    k_pg<<<GG, 256, 0, stream>>>(x, ei, ew, Wgf1, bcomb, Wf2, bf2, Qh, pens);
    // g_embs = Qh @ Wg + 32*bg
    k_gemm<<<dim3(128, 2), 256, 0, stream>>>(Qh, Wg, bg32, g_embs,
                                             nullptr, nullptr, nullptr, GG, 64, 128, 0);

    // Parallel CSR build over pos_edges
    k_cnt<<<EP / 256, 256, 0, stream>>>(pos + EP, icnt_g);
    k_scan<<<1, 256, 0, stream>>>(icnt_g, off_g, cur_g, dinv);
    k_place<<<EP / 256, 256, 0, stream>>>(pos, dinv, cur_g, csr_src, csr_nrm);

    // h = relu((A g_embs) @ Wc1 + bc1)
    k_gather128<<<GG, 128, 0, stream>>>(off_g, icnt_g, csr_src, csr_nrm, dinv, g_embs, ga);
    k_gemm<<<dim3(128, 4), 256, 0, stream>>>(ga, Wc1, bc1, h,
                                             nullptr, nullptr, nullptr, GG, 128, 256, 1);

    // mu/ls = (A h) @ {Wmu,Wls} + {bmu,bls}
    k_gather256<<<GG, 256, 0, stream>>>(off_g, icnt_g, csr_src, csr_nrm, dinv, h, ha);
    k_gemm<<<dim3(128, 4), 256, 0, stream>>>(ha, Wmu, bmu, mu_arr,
                                             Wls, bls, ls_arr, GG, 256, 128, 0);
    k_fin_z<<<GG, 128, 0, stream>>>(mu_arr, ls_arr, eps, emb, zc, klp);

    // A = zc@W_lin1+b, B = zc@W_lin2+b
    k_gemm<<<dim3(128, 8), 256, 0, stream>>>(zc, Wl1, bl1, Abuf,
                                             Wl2, bl2, Bbuf, GG, 256, 256, 0);

    // Edge predictions + scalars (16 edges/block)
    k_pred<<<(2 * EP) / 16, 256, 0, stream>>>(Abuf, Bbuf, pos, neg, out, predp);
    k_final<<<1, 256, 0, stream>>>(pens, klp, predp, out);
}